// Round 16
// baseline (150.565 us; speedup 1.0000x reference)
//
#include <hip/hip_runtime.h>
#include <hip/hip_bf16.h>

#define SN 524288   // columns of the (64, SN) view of x

typedef float f32x4 __attribute__((ext_vector_type(4)));
typedef short bf16x8 __attribute__((ext_vector_type(8)));
typedef unsigned int u32x4 __attribute__((ext_vector_type(4)));

__device__ inline unsigned short f2bf(float v) {
  __hip_bfloat16 h = __float2bfloat16(v);
  unsigned short u; __builtin_memcpy(&u, &h, 2); return u;
}
__device__ inline float bf2f(unsigned short b) {
  unsigned u = ((unsigned)b) << 16; float f; __builtin_memcpy(&f, &u, 4); return f;
}

// ---------------- Kernel A: build Ct[c*64 + i] = C[i][c], C = [B | M21] (64 x 128) ---
__global__ __launch_bounds__(256) void k_buildC(const float* __restrict__ L,
                                                const float* __restrict__ R,
                                                float* __restrict__ Ct) {
  __shared__ float4 Ls[4096];  // L (128x128) XOR-swizzled in float4 units
  const float4* L4 = (const float4*)L;
  #pragma unroll
  for (int it = 0; it < 16; ++it) {
    int idx = threadIdx.x + it * 256;
    int row = idx >> 5, t4 = idx & 31;
    Ls[(row << 5) + (t4 ^ (row & 7))] = L4[idx];
  }
  __syncthreads();
  int g = blockIdx.x * 256 + threadIdx.x;  // 0..8191
  int c = g >> 6;                          // column of C, uniform per wave
  int i = g & 63;                          // row of C = lane
  if (c < 64) {
    float d1 = 0.f, d2 = 0.f;
    #pragma unroll
    for (int t4 = 0; t4 < 32; ++t4) {
      float4 a1 = Ls[(i << 5) + (t4 ^ (i & 7))];
      float4 b1 = Ls[(c << 5) + (t4 ^ (c & 7))];
      float4 a2 = Ls[((64 + i) << 5) + (t4 ^ (i & 7))];
      float4 b2 = Ls[((64 + c) << 5) + (t4 ^ (c & 7))];
      d1 += a1.x * b1.x + a1.y * b1.y + a1.z * b1.z + a1.w * b1.w;
      d2 += a2.x * b2.x + a2.y * b2.y + a2.z * b2.z + a2.w * b2.w;
    }
    float val = 2.0f * (d1 + d2 + R[i * 64 + c] - R[c * 64 + i]);
    if (i == c) val += 4e-8f;
    Ct[c * 64 + i] = val;
  } else {
    int jj = c - 64;
    float d = 0.f;
    #pragma unroll
    for (int t4 = 0; t4 < 32; ++t4) {
      float4 a = Ls[(i << 5) + (t4 ^ (i & 7))];
      float4 b = Ls[((64 + jj) << 5) + (t4 ^ (jj & 7))];
      d += a.x * b.x + a.y * b.y + a.z * b.z + a.w * b.w;
    }
    Ct[c * 64 + i] = d;
  }
}

// ---------------- Kernel B: Gauss-Jordan solve, emit A in MFMA fragment format ----
// AF[ld*64 + f*4 + j2]: lane ld = (i&15) + 16*(k_local>>3); frag f = (g*2+kh)*2+part
// (g = i>>4, kh = k>>5, part 0=hi/1=lo bf16 split); dword j2 packs the bf16 pair for
// k_local bits [2:1], bit 0 = position in pair. k-map: k_local = (lane>>4)*8 + elem —
// IDENTICAL formula for HW A-op and B-op (mirror symmetry, validated on HW by R14's
// pass). R16 uses AF as the B-operand (A-matrix cols = output i).
__global__ __launch_bounds__(256) void k_solve(const float* __restrict__ Ct,
                                               unsigned int* __restrict__ AF) {
  __shared__ float colbuf[2][64];
  __shared__ __align__(16) float rowbuf[2][128];
  const int r = threadIdx.x & 63;
  const int cgrp = threadIdx.x >> 6;
  float creg[32];
  #pragma unroll
  for (int cc = 0; cc < 32; ++cc)
    creg[cc] = Ct[(cgrp * 32 + cc) * 64 + r];
  #pragma unroll
  for (int p = 0; p < 64; ++p) {
    const int pb = p & 1, pc = p >> 5, pi = p & 31;
    if (cgrp == pc) colbuf[pb][r] = creg[pi];
    if (r == p) {
      #pragma unroll
      for (int cc = 0; cc < 32; ++cc) rowbuf[pb][cgrp * 32 + cc] = creg[cc];
    }
    __syncthreads();
    const float f = colbuf[pb][r];
    const float inv = 1.0f / colbuf[pb][p];
    if (r == p) {
      #pragma unroll
      for (int cc = 0; cc < 32; ++cc) creg[cc] *= inv;
    } else {
      const float gg = f * inv;
      #pragma unroll
      for (int c4 = 0; c4 < 8; ++c4) {
        const float4 pv = *(const float4*)&rowbuf[pb][cgrp * 32 + c4 * 4];
        creg[c4 * 4 + 0] -= gg * pv.x;
        creg[c4 * 4 + 1] -= gg * pv.y;
        creg[c4 * 4 + 2] -= gg * pv.z;
        creg[c4 * 4 + 3] -= gg * pv.w;
      }
    }
  }
  // creg[cc] (cgrp>=2) = A[r][k = (cgrp-2)*32 + cc];  emit with i=r, kh=cgrp-2
  if (cgrp >= 2) {
    const int kh = cgrp - 2;
    const int g = r >> 4;
    const int rl = r & 15;
    #pragma unroll
    for (int p2 = 0; p2 < 16; ++p2) {
      const int cc = p2 * 2;
      const float v0 = creg[cc], v1 = creg[cc + 1];
      const unsigned short h0 = f2bf(v0), h1 = f2bf(v1);
      const unsigned short l0 = f2bf(v0 - bf2f(h0)), l1 = f2bf(v1 - bf2f(h1));
      const int ld = rl + 16 * (cc >> 3);
      const int j2 = (cc & 7) >> 1;
      AF[ld * 64 + ((g * 2 + kh) * 2 + 0) * 4 + j2] = ((unsigned)h1 << 16) | h0;
      AF[ld * 64 + ((g * 2 + kh) * 2 + 1) * 4 + j2] = ((unsigned)l1 << 16) | l0;
    }
  }
}

// -------- Kernel C: out = A @ X via bf16-split MFMA, operand-SWAPPED --------------
// X in the A-operand (M = 16 j-cols/block), A-matrix in the B-operand (N = i).
// ONE wave per block, NO LDS, NO barriers: lane l loads its X fragment directly
// from global (16 global_load_dword, each hitting 4 full 64B lines), converts to
// bf16 hi/lo in-reg, runs 24 MFMAs (4 i-tiles x 2 k-halves x {XhAh, XlAh, XhAl}),
// then stores acc[g] as dwordx4 (C/D row = (lane>>4)*4+reg = 4 CONSECUTIVE j ->
// 64B-coalesced). All memory ops independent -> latency hidden by ~4 waves/SIMD
// across 32768 blocks. MFMA acc chains cannot be strip-mined by the backend.
__global__ __launch_bounds__(64) void k_apply(const float* __restrict__ x,
                                              const unsigned int* __restrict__ AF,
                                              float* __restrict__ out) {
  const int l = threadIdx.x;
  const int l15 = l & 15;
  const int lg = l >> 4;
  const long jb = (long)blockIdx.x * 16;  // j-tile base

  // A-matrix B-operand fragments: 16 x dwordx4 per lane (L2-hot, 16 KB table)
  bf16x8 bfr[16];
  {
    const u32x4* AF4 = (const u32x4*)AF;
    #pragma unroll
    for (int f = 0; f < 16; ++f) {
      u32x4 v = AF4[l * 16 + f];
      __builtin_memcpy(&bfr[f], &v, 16);
    }
  }

  // X A-operand raw loads: xr[kh][e] = x[(kh*32 + lg*8 + e)][jb + l15]
  float xr[2][8];
  const float* __restrict__ xp = x + (long)lg * 8 * SN + jb + l15;
  #pragma unroll
  for (int kh = 0; kh < 2; ++kh)
    #pragma unroll
    for (int e = 0; e < 8; ++e)
      xr[kh][e] = xp[((long)kh * 32 + e) * SN];

  // convert to bf16 hi/lo fragments
  bf16x8 xh[2], xl[2];
  #pragma unroll
  for (int kh = 0; kh < 2; ++kh)
    #pragma unroll
    for (int e = 0; e < 8; ++e) {
      const float v = xr[kh][e];
      const unsigned short h = f2bf(v);
      const unsigned short q = f2bf(v - bf2f(h));
      xh[kh][e] = (short)h;
      xl[kh][e] = (short)q;
    }

  f32x4 acc[4];
  #pragma unroll
  for (int g = 0; g < 4; ++g) acc[g] = (f32x4){0.f, 0.f, 0.f, 0.f};

  #pragma unroll
  for (int g = 0; g < 4; ++g)
    #pragma unroll
    for (int kh = 0; kh < 2; ++kh) {
      const bf16x8 ah = bfr[(g * 2 + kh) * 2 + 0];
      const bf16x8 al = bfr[(g * 2 + kh) * 2 + 1];
      acc[g] = __builtin_amdgcn_mfma_f32_16x16x32_bf16(xh[kh], ah, acc[g], 0, 0, 0);
      acc[g] = __builtin_amdgcn_mfma_f32_16x16x32_bf16(xl[kh], ah, acc[g], 0, 0, 0);
      acc[g] = __builtin_amdgcn_mfma_f32_16x16x32_bf16(xh[kh], al, acc[g], 0, 0, 0);
    }

  // store: lane holds j = jb + lg*4 + reg (consecutive!), col i = g*16 + l15
  #pragma unroll
  for (int g = 0; g < 4; ++g) {
    float* dst = out + (long)(g * 16 + l15) * SN + jb + lg * 4;
    __builtin_nontemporal_store(acc[g], (f32x4*)dst);
  }
}

extern "C" void kernel_launch(void* const* d_in, const int* in_sizes, int n_in,
                              void* d_out, int out_size, void* d_ws, size_t ws_size,
                              hipStream_t stream) {
  const float* x = (const float*)d_in[0];  // 524288 x 64
  const float* L = (const float*)d_in[1];  // 128 x 128
  const float* R = (const float*)d_in[2];  // 64 x 64
  float* out = (float*)d_out;
  float* Ct = (float*)d_ws;                           // 128*64 f32 = 32 KB
  unsigned int* AF = (unsigned int*)(Ct + 128 * 64);  // 64*64 u32 = 16 KB
  k_buildC<<<32, 256, 0, stream>>>(L, R, Ct);
  k_solve<<<1, 256, 0, stream>>>(Ct, AF);
  k_apply<<<32768, 64, 0, stream>>>(x, AF, out);
}